// Round 11
// baseline (7402.431 us; speedup 1.0000x reference)
//
#include <hip/hip_runtime.h>
#include <stdint.h>
#include <math.h>

#define N_PART 8192
#define T_STEPS 1024
#define UKNOTS 130            // coarse u-knots k=0..129, u=k/128 (cubic source grid)
#define SIKNOTS 68            // sI-knots j=0..67, sI = SI_LO + j*SI_H
#define M2TOT (UKNOTS*SIKNOTS)
#define FKN 2049              // fine linear grid in u: entries c=0..2048, u=c/2048
#define SI_LO 0.49375f
#define SI_H  0.00625f
#define LOGNU 3.6862316527834183f
#define LOG8192 9.010913347279288f
#define DD2LW 5000.0f                 // lw = LOGNU - 5000*dd, dd=(V-vm)^2
#define DD2E  7213.4752044448170f     // 5000*log2(e)

typedef float vfloat4 __attribute__((ext_vector_type(4)));   // native vec for nontemporal builtins

// LDS-only barrier: orders ds ops without draining outstanding global stores
// (__syncthreads emits s_waitcnt vmcnt(0) lgkmcnt(0) which stalls on hist writes).
#define BAR_LGKM() asm volatile("s_waitcnt lgkmcnt(0)\n\ts_barrier" ::: "memory")

// ---------------- Threefry-2x32 (exact JAX semantics) ----------------
__device__ __forceinline__ uint32_t rotl32(uint32_t x, int d){ return (x<<d)|(x>>(32-d)); }

__device__ __forceinline__ void tf2x32(uint32_t k0, uint32_t k1, uint32_t c0, uint32_t c1,
                                       uint32_t& o0, uint32_t& o1){
  uint32_t ks2 = k0 ^ k1 ^ 0x1BD11BDAu;
  uint32_t x0 = c0 + k0, x1 = c1 + k1;
  #define TFR(r) { x0 += x1; x1 = rotl32(x1, r); x1 ^= x0; }
  TFR(13) TFR(15) TFR(26) TFR(6)
  x0 += k1;  x1 += ks2 + 1u;
  TFR(17) TFR(29) TFR(16) TFR(24)
  x0 += ks2; x1 += k0 + 2u;
  TFR(13) TFR(15) TFR(26) TFR(6)
  x0 += k0;  x1 += k1 + 3u;
  TFR(17) TFR(29) TFR(16) TFR(24)
  x0 += k1;  x1 += ks2 + 4u;
  TFR(13) TFR(15) TFR(26) TFR(6)
  x0 += ks2; x1 += k0 + 5u;
  #undef TFR
  o0 = x0; o1 = x1;
}

__device__ __forceinline__ float erfinv_xla(float x){
  float w = -log1pf(-x*x);
  float p;
  if (w < 5.0f){
    w -= 2.5f;
    p = 2.81022636e-08f;
    p = fmaf(p, w, 3.43273939e-07f);
    p = fmaf(p, w, -3.5233877e-06f);
    p = fmaf(p, w, -4.39150654e-06f);
    p = fmaf(p, w, 0.00021858087f);
    p = fmaf(p, w, -0.00125372503f);
    p = fmaf(p, w, -0.00417768164f);
    p = fmaf(p, w, 0.246640727f);
    p = fmaf(p, w, 1.50140941f);
  } else {
    w = sqrtf(w) - 3.0f;
    p = -0.000200214257f;
    p = fmaf(p, w, 0.000100950558f);
    p = fmaf(p, w, 0.00134934322f);
    p = fmaf(p, w, -0.00367342844f);
    p = fmaf(p, w, 0.00573950773f);
    p = fmaf(p, w, -0.0076224613f);
    p = fmaf(p, w, 0.00943887047f);
    p = fmaf(p, w, 1.00167406f);
    p = fmaf(p, w, 2.83297682f);
  }
  return p * x;
}

// ---------------- kernel 1: per-step keys + u0 ----------------
__global__ void k_keys(uint32_t* __restrict__ knKeys, float* __restrict__ u0Tab){
  int t = blockIdx.x*blockDim.x + threadIdx.x;
  if (t >= T_STEPS) return;
  uint32_t kA0,kA1,kB0,kB1;
  tf2x32(0u,42u, 0u,0u, kA0,kA1);
  tf2x32(0u,42u, 0u,1u, kB0,kB1);
  auto splitElem = [&](uint32_t kk0, uint32_t kk1, int idx)->uint32_t{
    uint32_t o0,o1;
    if (idx < T_STEPS){ tf2x32(kk0,kk1,(uint32_t)idx,(uint32_t)(T_STEPS+idx),o0,o1); return o0; }
    int i = idx - T_STEPS;
    tf2x32(kk0,kk1,(uint32_t)i,(uint32_t)(T_STEPS+i),o0,o1); return o1;
  };
  uint32_t n0 = splitElem(kA0,kA1, 2*t);
  uint32_t n1 = splitElem(kA0,kA1, 2*t+1);
  uint32_t r0 = splitElem(kB0,kB1, 2*t);
  uint32_t r1 = splitElem(kB0,kB1, 2*t+1);
  knKeys[2*t] = n0; knKeys[2*t+1] = n1;
  uint32_t o0,o1; tf2x32(r0,r1,0u,0u,o0,o1);
  u0Tab[t] = __uint_as_float((o0>>9) | 0x3f800000u) - 1.0f;
}

// ---------------- kernel 2: noise table ----------------
__global__ void k_noise(const uint32_t* __restrict__ knKeys, float* __restrict__ noiseTab){
  int t = blockIdx.x;
  uint32_t k0 = knKeys[2*t], k1 = knKeys[2*t+1];
  const int half = N_PART/2;
  const float lo = -0.99999994f;
  for (int i = threadIdx.x; i < half; i += blockDim.x){
    uint32_t o0,o1; tf2x32(k0,k1,(uint32_t)i,(uint32_t)(half+i),o0,o1);
    float ua = __uint_as_float((o0>>9)|0x3f800000u) - 1.0f;
    float ub = __uint_as_float((o1>>9)|0x3f800000u) - 1.0f;
    float va = fmaxf(lo, ua*2.0f + lo);
    float vb = fmaxf(lo, ub*2.0f + lo);
    float na = 1.4142135623730951f * erfinv_xla(va);
    float nb = 1.4142135623730951f * erfinv_xla(vb);
    noiseTab[(size_t)t*N_PART + i]        = 0.005f * na;
    noiseTab[(size_t)t*N_PART + half + i] = 0.005f * nb;
  }
}

// ---------------- kernel 3: (u, sI)-grid MLP GEMM ----------------
__global__ __launch_bounds__(256) void k_gemm(
    const float* __restrict__ W1, const float* __restrict__ b1,
    const float* __restrict__ W2, const float* __restrict__ b2,
    const float* __restrict__ W3, float* __restrict__ Zpart)
{
  __shared__ float sA[32][64];
  __shared__ float sB[32][129];
  __shared__ float sSoc[64], sSI[64];
  __shared__ float sRed[64][17];

  const int tid = threadIdx.x;
  const int m0 = blockIdx.x * 64;
  const int n0 = blockIdx.y * 128;

  if (tid < 64){
    int r = m0 + tid; if (r >= M2TOT) r = M2TOT-1;
    int k = r / SIKNOTS;
    int j = r - k*SIKNOTS;
    float u = (float)k * (1.0f/128.0f);
    sSoc[tid] = u*u;
    sSI[tid]  = SI_LO + SI_H * (float)j;
  }
  __syncthreads();

  const int tx = tid & 15;
  const int ty = tid >> 4;
  float acc[4][8];
  #pragma unroll
  for (int i=0;i<4;i++)
    #pragma unroll
    for (int q=0;q<8;q++) acc[i][q] = 0.0f;

  for (int kc = 0; kc < 1024; kc += 32){
    {
      int base = tid*8;
      int jj = base >> 6;
      int mm = base & 63;
      int j = kc + jj;
      float w0 = W1[2*j], w1v = W1[2*j+1], bb = b1[j];
      #pragma unroll
      for (int e=0;e<8;e++){
        int m = mm + e;
        float pre = sSoc[m]*w0 + sSI[m]*w1v + bb;
        sA[jj][m] = 1.0f/(1.0f + expf(-pre));
      }
    }
    {
      int nl = tid & 127;
      int h  = tid >> 7;
      const float* src = W2 + (size_t)(n0 + nl)*1024 + kc + h*16;
      float4 v0 = *(const float4*)(src+0);
      float4 v1 = *(const float4*)(src+4);
      float4 v2 = *(const float4*)(src+8);
      float4 v3 = *(const float4*)(src+12);
      int kb = h*16;
      sB[kb+ 0][nl]=v0.x; sB[kb+ 1][nl]=v0.y; sB[kb+ 2][nl]=v0.z; sB[kb+ 3][nl]=v0.w;
      sB[kb+ 4][nl]=v1.x; sB[kb+ 5][nl]=v1.y; sB[kb+ 6][nl]=v1.z; sB[kb+ 7][nl]=v1.w;
      sB[kb+ 8][nl]=v2.x; sB[kb+ 9][nl]=v2.y; sB[kb+10][nl]=v2.z; sB[kb+11][nl]=v2.w;
      sB[kb+12][nl]=v3.x; sB[kb+13][nl]=v3.y; sB[kb+14][nl]=v3.z; sB[kb+15][nl]=v3.w;
    }
    __syncthreads();
    #pragma unroll
    for (int kk=0;kk<32;kk++){
      float a_[4], b_[8];
      #pragma unroll
      for (int i=0;i<4;i++) a_[i] = sA[kk][ty*4+i];
      #pragma unroll
      for (int q=0;q<8;q++) b_[q] = sB[kk][tx*8+q];
      #pragma unroll
      for (int i=0;i<4;i++)
        #pragma unroll
        for (int q=0;q<8;q++) acc[i][q] = fmaf(a_[i], b_[q], acc[i][q]);
    }
    __syncthreads();
  }
  float part[4] = {0.f,0.f,0.f,0.f};
  #pragma unroll
  for (int q=0;q<8;q++){
    int n = n0 + tx*8 + q;
    float bb = b2[n], w3 = W3[n];
    #pragma unroll
    for (int i=0;i<4;i++){
      float h = 1.0f/(1.0f + expf(-(acc[i][q] + bb)));
      part[i] = fmaf(w3, h, part[i]);
    }
  }
  #pragma unroll
  for (int i=0;i<4;i++) sRed[ty*4+i][tx] = part[i];
  __syncthreads();
  if (tid < 64){
    int r = m0 + tid;
    if (r < M2TOT){
      float s = 0.0f;
      #pragma unroll
      for (int x=0;x<16;x++) s += sRed[tid][x];
      Zpart[(size_t)blockIdx.y*M2TOT + r] = s;
    }
  }
}

// ---------------- kernel 4a: combine Z parts ----------------
__global__ void k_tabZ(const float* __restrict__ Zpart, const float* __restrict__ b3,
                       float* __restrict__ Z2D){
  int r = blockIdx.x*blockDim.x + threadIdx.x;
  if (r >= M2TOT) return;
  Z2D[r] = ((Zpart[r] + Zpart[M2TOT+r]) + Zpart[2*M2TOT+r]) + Zpart[3*M2TOT+r] + b3[0];
}

// ---------------- kernel 4b: per-(t,k) sI-interp + voc -> coarse G table ----------------
__global__ void k_tabG(const float* __restrict__ Z2D, const float* __restrict__ current,
                       float* __restrict__ Gtab){
  int m = blockIdx.x*blockDim.x + threadIdx.x;
  if (m >= T_STEPS*UKNOTS) return;
  int t = m / UKNOTS;
  int k = m - t*UKNOTS;
  float It = current[t];
  float sI = (It + 2.0f) * 0.25f;
  float x = (sI - SI_LO) * (1.0f/SI_H);
  int c = (int)x; if (c < 1) c = 1; if (c > 65) c = 65;
  float xi = x - (float)c;
  const float* zp = Z2D + k*SIKNOTS + (c-1);
  float y0 = zp[0], y1 = zp[1], y2 = zp[2], y3 = zp[3];
  float xm1 = xi - 1.0f, xm2 = xi - 2.0f, xp1 = xi + 1.0f;
  float w0 = -(1.0f/6.0f) * xi  * xm1 * xm2;
  float w1 =  0.5f        * xp1 * xm1 * xm2;
  float w2 = -0.5f        * xi  * xp1 * xm2;
  float w3 =  (1.0f/6.0f) * xi  * xp1 * xm1;
  float z = ((w0*y0 + w1*y1) + w2*y2) + w3*y3;
  double u = (double)k / 128.0;
  double s = u*u;
  const double vL=-1.59614486, v0=4.13646328, gam=0.63726463, alp=1.40174122, bet=2.54478965;
  double voc = vL + (v0-vL)*exp(gam*(s-1.0)) + alp*vL*(s-1.0)
             + (1.0-alp)*vL*(exp(-bet) - exp(-bet*sqrt(s)));
  Gtab[m] = (float)voc - It*z;
}

// ---------------- kernel 4c: coarse cubic -> fine scalar table ----------------
__device__ __forceinline__ float cubicEval(const float* __restrict__ g, int cf){
  float x = (float)cf * (1.0f/16.0f);
  int cc = (int)x; if (cc > 127) cc = 127;
  float xi = x - (float)cc;
  float y0 = (cc == 0) ? g[1] : g[cc-1];   // even mirror in u
  float y1 = g[cc], y2 = g[cc+1], y3 = g[cc+2];
  float xm1 = xi - 1.0f, xm2 = xi - 2.0f, xp1 = xi + 1.0f;
  float w0 = -(1.0f/6.0f) * xi  * xm1 * xm2;
  float w1 =  0.5f        * xp1 * xm1 * xm2;
  float w2 = -0.5f        * xi  * xp1 * xm2;
  float w3 =  (1.0f/6.0f) * xi  * xp1 * xm1;
  return ((w0*y0 + w1*y1) + w2*y2) + w3*y3;
}
__global__ void k_tabFine(const float* __restrict__ Gtab, float* __restrict__ TabF){
  int m = blockIdx.x*blockDim.x + threadIdx.x;
  if (m >= T_STEPS*FKN) return;
  int t = m / FKN;
  int c = m - t*FKN;
  TabF[m] = cubicEval(Gtab + t*UKNOTS, c);
}

// linear interp on scalar fine table (LDS)
__device__ __forceinline__ float interpS(const float* __restrict__ tab, float s){
  float x = sqrtf(s) * 2048.0f;
  float cf = floorf(x);
  cf = fminf(cf, 2047.0f);
  int c = (int)cf;
  float xi = x - cf;
  float y0 = tab[c], y1 = tab[c+1];
  return fmaf(xi, y1 - y0, y0);
}

// ---------------- kernel 5: sequential particle filter (single block, 1024 thr) ----------------
// R9 structure + (a) B1/B3 are lgkm-only barriers (global stores never gate them),
// (b) vHist store moved after B2 so B2's vmcnt(0) drains only the idxG atomics,
// (c) nontemporal hist stores (keep L2 for idxG/TabF).
__global__ __launch_bounds__(1024) void k_filter(
    const float* __restrict__ soc_init, const float* __restrict__ current,
    const float* __restrict__ vmeas,   const float* __restrict__ Ecrit,
    const float* __restrict__ TabF,    const float* __restrict__ noiseTab,
    const float* __restrict__ u0Tab,   int* __restrict__ idxG,
    float* __restrict__ vHist, float* __restrict__ sHist,
    long strideT, long strideP, float* __restrict__ lossOut)
{
  __shared__ __align__(16) float socP[N_PART];     // 32 KiB (exact f32 propagated state)
  __shared__ __align__(16) float tabF[2][2052];    // 16.4 KiB dbuf
  __shared__ float ddW[16];
  __shared__ float sWv[16];

  const int tid = threadIdx.x;
  const int lane = tid & 63;
  const int wv = tid >> 6;
  const float ec = Ecrit[0];

  // prologue
  tabF[0][tid]      = TabF[tid];
  tabF[0][1024+tid] = TabF[1024+tid];
  if (tid == 0) tabF[0][2048] = TabF[2048];
  const float4* nzp = (const float4*)noiseTab + tid*2;
  float4 nzA = nzp[0], nzB = nzp[1];
  float soc[8], V[8];
  __syncthreads();
  #pragma unroll
  for (int k=0;k<8;k++){
    float s = soc_init[tid*8+k];
    soc[k] = s;
    V[k] = interpS(tabF[0], s);
  }
  float loss = 0.0f;
  float Iprev = current[0];

  for (int t=0; t<T_STEPS; t++){
    const int cur = t & 1, nxt = cur ^ 1;
    const int tagBase = t << 13;

    // prefetch next-step table + noise into registers
    int tn = (t+1 < T_STEPS) ? t+1 : t;
    const float* tRow = TabF + (size_t)tn * FKN;
    float pf0 = tRow[tid];
    float pf1 = tRow[1024+tid];
    float pf2 = 0.0f;
    if (tid == 0) pf2 = tRow[2048];
    const float4* nzn = (const float4*)(noiseTab + (size_t)tn*N_PART) + tid*2;
    float4 nzA2 = nzn[0], nzB2 = nzn[1];

    float It = current[t];
    float vm = vmeas[t];
    float u0 = u0Tab[t];
    float coef = -(Iprev / 26267.160775850585f) * ec;
    float nz[8] = {nzA.x,nzA.y,nzA.z,nzA.w,nzB.x,nzB.y,nzB.z,nzB.w};
    const float* tf = tabF[cur];

    // ---- phase 1: propagate + measure (socP write in LDS, exact f32) ----
    float dd[8];
    float dmin = INFINITY;
    #pragma unroll
    for (int k=0;k<8;k++){
      float s = fmaf(V[k], coef, soc[k]);
      s = s + nz[k];
      s = fminf(1.0f, fmaxf(s, 1e-10f));
      socP[tid*8+k] = s;
      float Vn = interpS(tf, s);
      V[k] = Vn;
      float d = Vn - vm;
      float q = d*d;
      dd[k] = q;
      dmin = fminf(dmin, q);
    }

    // wave min + exp prefix (wave frame)
    #pragma unroll
    for (int off=1; off<64; off<<=1) dmin = fminf(dmin, __shfl_xor(dmin, off));
    float ebase = DD2E * dmin;
    float run = 0.0f, cp[8];
    #pragma unroll
    for (int k=0;k<8;k++){
      float e = exp2f(fmaf(dd[k], -DD2E, ebase));
      run += e;
      cp[k] = run;
    }
    float sc = run;
    #pragma unroll
    for (int off=1; off<64; off<<=1){
      float o = __shfl_up(sc, (unsigned)off);
      if (lane >= off) sc += o;
    }
    float excl = __shfl_up(sc, 1);       // bitwise == prev lane's inclusive sc
    if (lane == 0) excl = 0.0f;
    if (lane == 63){ ddW[wv] = dmin; sWv[wv] = sc; }
    // commit prefetched table into the other buffer
    tabF[nxt][tid]      = pf0;
    tabF[nxt][1024+tid] = pf1;
    if (tid == 0) tabF[nxt][2048] = pf2;
    BAR_LGKM();                          // B1 (LDS-only ordering)

    // ---- combine wave stats (lanes 0..15 of every wave, redundant; normalized frames) ----
    float baseN = 0.0f, inclN = 0.0f, scaleN = 0.0f;
    if (lane < 16){
      float dv = ddW[lane];
      float dG = dv;
      #pragma unroll
      for (int off=1; off<16; off<<=1) dG = fminf(dG, __shfl_xor(dG, off));
      float ew = exp2f(-DD2E * (dv - dG));
      float pf = sWv[lane] * ew;
      #pragma unroll
      for (int off=1; off<16; off<<=1){
        float o = __shfl_up(pf, (unsigned)off);
        if (lane >= off) pf += o;
      }
      float Sv = __shfl(pf, 15);
      float invS = 1.0f / Sv;
      float pfEx = __shfl_up(pf, 1);
      if (lane == 0) pfEx = 0.0f;
      baseN  = pfEx * invS;              // exclusive block prefix, normalized
      inclN  = pf * invS;                // inclusive; bitwise == next wave's baseN
      scaleN = ew * invS;
      if (tid == 0)
        loss = ((loss + (LOGNU - DD2LW*dG)) + logf(Sv)) - LOG8192;
    }
    float b0  = __shfl(baseN, wv);
    float bI  = __shfl(inclN, wv);
    float scl = __shfl(scaleN, wv);

    // ---- slot inversion + tagged GLOBAL scatter (bitwise-exact seams, owners only) ----
    float scl8 = scl * 8192.0f;
    float b8   = fmaf(b0, 8192.0f, -u0);       // wave base in slot units
    float bth  = fmaf(excl, scl8, b8);
    int aPrev = __float2int_rd(bth);
    if (aPrev < -1) aPrev = -1;
    #pragma unroll
    for (int k=0;k<8;k++){
      int i = tid*8 + k;
      int a;
      if (i == N_PART-1){
        a = N_PART-1;
      } else if (k == 7){
        if (lane == 63) a = __float2int_rd(fmaf(bI, 8192.0f, -u0));  // == next wave's aPrev
        else            a = __float2int_rd(fmaf(sc, scl8, b8));      // == next thread's aPrev
        if (a > N_PART-1) a = N_PART-1;
      } else {
        a = __float2int_rd(fmaf(cp[k], scl8, bth));
        if (a > N_PART-1) a = N_PART-1;
      }
      if (a < aPrev) a = aPrev;
      int st = aPrev + 1;
      if (a >= st){                              // owners only
        int tag = tagBase + i;
        atomicMax(&idxG[st], tag);
        for (int r = (st>>9)+1; (r<<9) <= a; ++r)
          atomicMax(&idxG[r<<9], tag);           // 512-region anchors
      }
      aPrev = a;
    }
    __syncthreads();                     // B2 (drains idxG atomics + socP; hist writes deferred)

    // ---- hist V write (deferred past B2 so its vmcnt never gates the barrier) ----
    if (strideP == 1){
      vfloat4 a = {V[0],V[1],V[2],V[3]}, b = {V[4],V[5],V[6],V[7]};
      vfloat4* dst = (vfloat4*)(vHist + (size_t)t*strideT + tid*8);
      __builtin_nontemporal_store(a, dst);
      __builtin_nontemporal_store(b, dst+1);
    } else {
      #pragma unroll
      for (int k=0;k<8;k++) vHist[(size_t)t*strideT + (size_t)(tid*8+k)*strideP] = V[k];
    }

    // ---- slot phase: agent-scope idxG reads (L1-bypass), wave max-scan, LDS gather ----
    unsigned long long q01 = __hip_atomic_load((unsigned long long*)&idxG[tid*8+0], __ATOMIC_RELAXED, __HIP_MEMORY_SCOPE_AGENT);
    unsigned long long q23 = __hip_atomic_load((unsigned long long*)&idxG[tid*8+2], __ATOMIC_RELAXED, __HIP_MEMORY_SCOPE_AGENT);
    unsigned long long q45 = __hip_atomic_load((unsigned long long*)&idxG[tid*8+4], __ATOMIC_RELAXED, __HIP_MEMORY_SCOPE_AGENT);
    unsigned long long q67 = __hip_atomic_load((unsigned long long*)&idxG[tid*8+6], __ATOMIC_RELAXED, __HIP_MEMORY_SCOPE_AGENT);
    int sl[8] = { (int)(uint32_t)q01, (int)(uint32_t)(q01>>32),
                  (int)(uint32_t)q23, (int)(uint32_t)(q23>>32),
                  (int)(uint32_t)q45, (int)(uint32_t)(q45>>32),
                  (int)(uint32_t)q67, (int)(uint32_t)(q67>>32) };
    int pm = sl[0];
    #pragma unroll
    for (int k=1;k<8;k++) pm = max(pm, sl[k]);
    int scn = pm;
    #pragma unroll
    for (int off=1; off<64; off<<=1){
      int o = __shfl_up(scn, (unsigned)off);
      if (lane >= off) scn = max(scn, o);
    }
    int ex = __shfl_up(scn, 1);
    if (lane == 0) ex = -1;              // wave-chunk start covered by 512-anchor
    float sn[8];
    int run2 = ex;
    #pragma unroll
    for (int k=0;k<8;k++){
      run2 = max(run2, sl[k]);
      int idx = run2 - tagBase;
      if (idx < 0 || idx > N_PART-1) idx = tid*8+k;   // safety net (should not trigger)
      sn[k] = socP[idx];
    }
    if (strideP == 1){
      vfloat4 a = {sn[0],sn[1],sn[2],sn[3]}, b = {sn[4],sn[5],sn[6],sn[7]};
      vfloat4* dst = (vfloat4*)(sHist + (size_t)t*strideT + tid*8);
      __builtin_nontemporal_store(a, dst);
      __builtin_nontemporal_store(b, dst+1);
    } else {
      #pragma unroll
      for (int k=0;k<8;k++) sHist[(size_t)t*strideT + (size_t)(tid*8+k)*strideP] = sn[k];
    }
    #pragma unroll
    for (int k=0;k<8;k++) soc[k] = sn[k];
    Iprev = It;
    nzA = nzA2; nzB = nzB2;
    BAR_LGKM();                          // B3 (WAR on socP; LDS-only ordering)
  }
  if (tid == 0) lossOut[0] = loss;
}

// ---------------- kernel 6: (T,N) -> (N,T) transpose ----------------
__global__ void k_transpose(const float* __restrict__ vS, const float* __restrict__ sS,
                            float* __restrict__ outV, float* __restrict__ outS){
  __shared__ float tile[32][33];
  const float* src = blockIdx.z ? sS : vS;
  float* dst = blockIdx.z ? outS : outV;
  int t0 = blockIdx.x*32, n0 = blockIdx.y*32;
  int tx = threadIdx.x, ty = threadIdx.y;
  #pragma unroll
  for (int r=0;r<4;r++)
    tile[ty+8*r][tx] = src[(size_t)(t0+ty+8*r)*N_PART + n0 + tx];
  __syncthreads();
  #pragma unroll
  for (int r=0;r<4;r++)
    dst[(size_t)(n0+ty+8*r)*T_STEPS + t0 + tx] = tile[tx][ty+8*r];
}

extern "C" void kernel_launch(void* const* d_in, const int* in_sizes, int n_in,
                              void* d_out, int out_size, void* d_ws, size_t ws_size,
                              hipStream_t stream){
  const float* soc_init = (const float*)d_in[0];
  const float* current  = (const float*)d_in[1];
  const float* vmeas    = (const float*)d_in[2];
  const float* W1 = (const float*)d_in[3];
  const float* b1 = (const float*)d_in[4];
  const float* W2 = (const float*)d_in[5];
  const float* b2 = (const float*)d_in[6];
  const float* W3 = (const float*)d_in[7];
  const float* b3 = (const float*)d_in[8];
  const float* Ec = (const float*)d_in[9];

  float* outLoss = (float*)d_out;
  float* outV = outLoss + 1;
  float* outS = outV + (size_t)N_PART*T_STEPS;

  char* p = (char*)d_ws;
  auto carve = [&](size_t bytes)->char*{ char* r = p; p += (bytes + 255) & ~(size_t)255; return r; };
  uint32_t* knKeys  = (uint32_t*)carve((size_t)2*T_STEPS*4);
  float* u0Tab      = (float*)carve((size_t)T_STEPS*4);
  int*   idxG       = (int*)carve((size_t)N_PART*4);     // 0xAA poison < 0 == stale, no init
  float* Zpart      = (float*)carve((size_t)4*M2TOT*4);
  float* Z2D        = (float*)carve((size_t)M2TOT*4);
  float* Gtab       = (float*)carve((size_t)T_STEPS*UKNOTS*4);
  float* TabF       = (float*)carve((size_t)T_STEPS*FKN*4);
  float* noiseTab   = (float*)carve((size_t)N_PART*T_STEPS*4);
  float* vS         = (float*)carve((size_t)N_PART*T_STEPS*4);
  float* sS         = (float*)carve((size_t)N_PART*T_STEPS*4);
  bool useScratch   = ((size_t)(p - (char*)d_ws) <= ws_size);

  k_keys<<<dim3((T_STEPS+255)/256), dim3(256), 0, stream>>>(knKeys, u0Tab);
  k_noise<<<dim3(T_STEPS), dim3(256), 0, stream>>>(knKeys, noiseTab);
  k_gemm<<<dim3((M2TOT+63)/64, 4), dim3(256), 0, stream>>>(W1, b1, W2, b2, W3, Zpart);
  k_tabZ<<<dim3((M2TOT+255)/256), dim3(256), 0, stream>>>(Zpart, b3, Z2D);
  k_tabG<<<dim3((T_STEPS*UKNOTS+255)/256), dim3(256), 0, stream>>>(Z2D, current, Gtab);
  k_tabFine<<<dim3((T_STEPS*FKN+255)/256), dim3(256), 0, stream>>>(Gtab, TabF);

  if (useScratch){
    k_filter<<<dim3(1), dim3(1024), 0, stream>>>(soc_init, current, vmeas, Ec, TabF, noiseTab,
                                                 u0Tab, idxG, vS, sS, (long)N_PART, 1L, outLoss);
    k_transpose<<<dim3(T_STEPS/32, N_PART/32, 2), dim3(32,8), 0, stream>>>(vS, sS, outV, outS);
  } else {
    k_filter<<<dim3(1), dim3(1024), 0, stream>>>(soc_init, current, vmeas, Ec, TabF, noiseTab,
                                                 u0Tab, idxG, outV, outS, 1L, (long)T_STEPS, outLoss);
  }
}

// Round 12
// 6677.850 us; speedup vs baseline: 1.1085x; 1.1085x over previous
//
#include <hip/hip_runtime.h>
#include <stdint.h>
#include <math.h>

#define N_PART 8192
#define T_STEPS 1024
#define UKNOTS 130            // coarse u-knots k=0..129, u=k/128 (cubic source grid)
#define SIKNOTS 68            // sI-knots j=0..67, sI = SI_LO + j*SI_H
#define M2TOT (UKNOTS*SIKNOTS)
#define FKN 2049              // fine linear grid in u: entries c=0..2048, u=c/2048
#define SI_LO 0.49375f
#define SI_H  0.00625f
#define LOGNU 3.6862316527834183f
#define LOG8192 9.010913347279288f
#define DD2LW 5000.0f                 // lw = LOGNU - 5000*dd, dd=(V-vm)^2
#define DD2E  7213.4752044448170f     // 5000*log2(e)

// LDS-only barrier: orders ds ops without draining outstanding global stores.
// Used ONLY where no global-memory dependence crosses the barrier (B1, B3).
#define BAR_LGKM() asm volatile("s_waitcnt lgkmcnt(0)\n\ts_barrier" ::: "memory")

// ---------------- Threefry-2x32 (exact JAX semantics) ----------------
__device__ __forceinline__ uint32_t rotl32(uint32_t x, int d){ return (x<<d)|(x>>(32-d)); }

__device__ __forceinline__ void tf2x32(uint32_t k0, uint32_t k1, uint32_t c0, uint32_t c1,
                                       uint32_t& o0, uint32_t& o1){
  uint32_t ks2 = k0 ^ k1 ^ 0x1BD11BDAu;
  uint32_t x0 = c0 + k0, x1 = c1 + k1;
  #define TFR(r) { x0 += x1; x1 = rotl32(x1, r); x1 ^= x0; }
  TFR(13) TFR(15) TFR(26) TFR(6)
  x0 += k1;  x1 += ks2 + 1u;
  TFR(17) TFR(29) TFR(16) TFR(24)
  x0 += ks2; x1 += k0 + 2u;
  TFR(13) TFR(15) TFR(26) TFR(6)
  x0 += k0;  x1 += k1 + 3u;
  TFR(17) TFR(29) TFR(16) TFR(24)
  x0 += k1;  x1 += ks2 + 4u;
  TFR(13) TFR(15) TFR(26) TFR(6)
  x0 += ks2; x1 += k0 + 5u;
  #undef TFR
  o0 = x0; o1 = x1;
}

__device__ __forceinline__ float erfinv_xla(float x){
  float w = -log1pf(-x*x);
  float p;
  if (w < 5.0f){
    w -= 2.5f;
    p = 2.81022636e-08f;
    p = fmaf(p, w, 3.43273939e-07f);
    p = fmaf(p, w, -3.5233877e-06f);
    p = fmaf(p, w, -4.39150654e-06f);
    p = fmaf(p, w, 0.00021858087f);
    p = fmaf(p, w, -0.00125372503f);
    p = fmaf(p, w, -0.00417768164f);
    p = fmaf(p, w, 0.246640727f);
    p = fmaf(p, w, 1.50140941f);
  } else {
    w = sqrtf(w) - 3.0f;
    p = -0.000200214257f;
    p = fmaf(p, w, 0.000100950558f);
    p = fmaf(p, w, 0.00134934322f);
    p = fmaf(p, w, -0.00367342844f);
    p = fmaf(p, w, 0.00573950773f);
    p = fmaf(p, w, -0.0076224613f);
    p = fmaf(p, w, 0.00943887047f);
    p = fmaf(p, w, 1.00167406f);
    p = fmaf(p, w, 2.83297682f);
  }
  return p * x;
}

// ---------------- kernel 1: per-step keys + u0 ----------------
__global__ void k_keys(uint32_t* __restrict__ knKeys, float* __restrict__ u0Tab){
  int t = blockIdx.x*blockDim.x + threadIdx.x;
  if (t >= T_STEPS) return;
  uint32_t kA0,kA1,kB0,kB1;
  tf2x32(0u,42u, 0u,0u, kA0,kA1);
  tf2x32(0u,42u, 0u,1u, kB0,kB1);
  auto splitElem = [&](uint32_t kk0, uint32_t kk1, int idx)->uint32_t{
    uint32_t o0,o1;
    if (idx < T_STEPS){ tf2x32(kk0,kk1,(uint32_t)idx,(uint32_t)(T_STEPS+idx),o0,o1); return o0; }
    int i = idx - T_STEPS;
    tf2x32(kk0,kk1,(uint32_t)i,(uint32_t)(T_STEPS+i),o0,o1); return o1;
  };
  uint32_t n0 = splitElem(kA0,kA1, 2*t);
  uint32_t n1 = splitElem(kA0,kA1, 2*t+1);
  uint32_t r0 = splitElem(kB0,kB1, 2*t);
  uint32_t r1 = splitElem(kB0,kB1, 2*t+1);
  knKeys[2*t] = n0; knKeys[2*t+1] = n1;
  uint32_t o0,o1; tf2x32(r0,r1,0u,0u,o0,o1);
  u0Tab[t] = __uint_as_float((o0>>9) | 0x3f800000u) - 1.0f;
}

// ---------------- kernel 2: noise table ----------------
__global__ void k_noise(const uint32_t* __restrict__ knKeys, float* __restrict__ noiseTab){
  int t = blockIdx.x;
  uint32_t k0 = knKeys[2*t], k1 = knKeys[2*t+1];
  const int half = N_PART/2;
  const float lo = -0.99999994f;
  for (int i = threadIdx.x; i < half; i += blockDim.x){
    uint32_t o0,o1; tf2x32(k0,k1,(uint32_t)i,(uint32_t)(half+i),o0,o1);
    float ua = __uint_as_float((o0>>9)|0x3f800000u) - 1.0f;
    float ub = __uint_as_float((o1>>9)|0x3f800000u) - 1.0f;
    float va = fmaxf(lo, ua*2.0f + lo);
    float vb = fmaxf(lo, ub*2.0f + lo);
    float na = 1.4142135623730951f * erfinv_xla(va);
    float nb = 1.4142135623730951f * erfinv_xla(vb);
    noiseTab[(size_t)t*N_PART + i]        = 0.005f * na;
    noiseTab[(size_t)t*N_PART + half + i] = 0.005f * nb;
  }
}

// ---------------- kernel 3: (u, sI)-grid MLP GEMM ----------------
__global__ __launch_bounds__(256) void k_gemm(
    const float* __restrict__ W1, const float* __restrict__ b1,
    const float* __restrict__ W2, const float* __restrict__ b2,
    const float* __restrict__ W3, float* __restrict__ Zpart)
{
  __shared__ float sA[32][64];
  __shared__ float sB[32][129];
  __shared__ float sSoc[64], sSI[64];
  __shared__ float sRed[64][17];

  const int tid = threadIdx.x;
  const int m0 = blockIdx.x * 64;
  const int n0 = blockIdx.y * 128;

  if (tid < 64){
    int r = m0 + tid; if (r >= M2TOT) r = M2TOT-1;
    int k = r / SIKNOTS;
    int j = r - k*SIKNOTS;
    float u = (float)k * (1.0f/128.0f);
    sSoc[tid] = u*u;
    sSI[tid]  = SI_LO + SI_H * (float)j;
  }
  __syncthreads();

  const int tx = tid & 15;
  const int ty = tid >> 4;
  float acc[4][8];
  #pragma unroll
  for (int i=0;i<4;i++)
    #pragma unroll
    for (int q=0;q<8;q++) acc[i][q] = 0.0f;

  for (int kc = 0; kc < 1024; kc += 32){
    {
      int base = tid*8;
      int jj = base >> 6;
      int mm = base & 63;
      int j = kc + jj;
      float w0 = W1[2*j], w1v = W1[2*j+1], bb = b1[j];
      #pragma unroll
      for (int e=0;e<8;e++){
        int m = mm + e;
        float pre = sSoc[m]*w0 + sSI[m]*w1v + bb;
        sA[jj][m] = 1.0f/(1.0f + expf(-pre));
      }
    }
    {
      int nl = tid & 127;
      int h  = tid >> 7;
      const float* src = W2 + (size_t)(n0 + nl)*1024 + kc + h*16;
      float4 v0 = *(const float4*)(src+0);
      float4 v1 = *(const float4*)(src+4);
      float4 v2 = *(const float4*)(src+8);
      float4 v3 = *(const float4*)(src+12);
      int kb = h*16;
      sB[kb+ 0][nl]=v0.x; sB[kb+ 1][nl]=v0.y; sB[kb+ 2][nl]=v0.z; sB[kb+ 3][nl]=v0.w;
      sB[kb+ 4][nl]=v1.x; sB[kb+ 5][nl]=v1.y; sB[kb+ 6][nl]=v1.z; sB[kb+ 7][nl]=v1.w;
      sB[kb+ 8][nl]=v2.x; sB[kb+ 9][nl]=v2.y; sB[kb+10][nl]=v2.z; sB[kb+11][nl]=v2.w;
      sB[kb+12][nl]=v3.x; sB[kb+13][nl]=v3.y; sB[kb+14][nl]=v3.z; sB[kb+15][nl]=v3.w;
    }
    __syncthreads();
    #pragma unroll
    for (int kk=0;kk<32;kk++){
      float a_[4], b_[8];
      #pragma unroll
      for (int i=0;i<4;i++) a_[i] = sA[kk][ty*4+i];
      #pragma unroll
      for (int q=0;q<8;q++) b_[q] = sB[kk][tx*8+q];
      #pragma unroll
      for (int i=0;i<4;i++)
        #pragma unroll
        for (int q=0;q<8;q++) acc[i][q] = fmaf(a_[i], b_[q], acc[i][q]);
    }
    __syncthreads();
  }
  float part[4] = {0.f,0.f,0.f,0.f};
  #pragma unroll
  for (int q=0;q<8;q++){
    int n = n0 + tx*8 + q;
    float bb = b2[n], w3 = W3[n];
    #pragma unroll
    for (int i=0;i<4;i++){
      float h = 1.0f/(1.0f + expf(-(acc[i][q] + bb)));
      part[i] = fmaf(w3, h, part[i]);
    }
  }
  #pragma unroll
  for (int i=0;i<4;i++) sRed[ty*4+i][tx] = part[i];
  __syncthreads();
  if (tid < 64){
    int r = m0 + tid;
    if (r < M2TOT){
      float s = 0.0f;
      #pragma unroll
      for (int x=0;x<16;x++) s += sRed[tid][x];
      Zpart[(size_t)blockIdx.y*M2TOT + r] = s;
    }
  }
}

// ---------------- kernel 4a: combine Z parts ----------------
__global__ void k_tabZ(const float* __restrict__ Zpart, const float* __restrict__ b3,
                       float* __restrict__ Z2D){
  int r = blockIdx.x*blockDim.x + threadIdx.x;
  if (r >= M2TOT) return;
  Z2D[r] = ((Zpart[r] + Zpart[M2TOT+r]) + Zpart[2*M2TOT+r]) + Zpart[3*M2TOT+r] + b3[0];
}

// ---------------- kernel 4b: per-(t,k) sI-interp + voc -> coarse G table ----------------
__global__ void k_tabG(const float* __restrict__ Z2D, const float* __restrict__ current,
                       float* __restrict__ Gtab){
  int m = blockIdx.x*blockDim.x + threadIdx.x;
  if (m >= T_STEPS*UKNOTS) return;
  int t = m / UKNOTS;
  int k = m - t*UKNOTS;
  float It = current[t];
  float sI = (It + 2.0f) * 0.25f;
  float x = (sI - SI_LO) * (1.0f/SI_H);
  int c = (int)x; if (c < 1) c = 1; if (c > 65) c = 65;
  float xi = x - (float)c;
  const float* zp = Z2D + k*SIKNOTS + (c-1);
  float y0 = zp[0], y1 = zp[1], y2 = zp[2], y3 = zp[3];
  float xm1 = xi - 1.0f, xm2 = xi - 2.0f, xp1 = xi + 1.0f;
  float w0 = -(1.0f/6.0f) * xi  * xm1 * xm2;
  float w1 =  0.5f        * xp1 * xm1 * xm2;
  float w2 = -0.5f        * xi  * xp1 * xm2;
  float w3 =  (1.0f/6.0f) * xi  * xp1 * xm1;
  float z = ((w0*y0 + w1*y1) + w2*y2) + w3*y3;
  double u = (double)k / 128.0;
  double s = u*u;
  const double vL=-1.59614486, v0=4.13646328, gam=0.63726463, alp=1.40174122, bet=2.54478965;
  double voc = vL + (v0-vL)*exp(gam*(s-1.0)) + alp*vL*(s-1.0)
             + (1.0-alp)*vL*(exp(-bet) - exp(-bet*sqrt(s)));
  Gtab[m] = (float)voc - It*z;
}

// ---------------- kernel 4c: coarse cubic -> fine scalar table ----------------
__device__ __forceinline__ float cubicEval(const float* __restrict__ g, int cf){
  float x = (float)cf * (1.0f/16.0f);
  int cc = (int)x; if (cc > 127) cc = 127;
  float xi = x - (float)cc;
  float y0 = (cc == 0) ? g[1] : g[cc-1];   // even mirror in u
  float y1 = g[cc], y2 = g[cc+1], y3 = g[cc+2];
  float xm1 = xi - 1.0f, xm2 = xi - 2.0f, xp1 = xi + 1.0f;
  float w0 = -(1.0f/6.0f) * xi  * xm1 * xm2;
  float w1 =  0.5f        * xp1 * xm1 * xm2;
  float w2 = -0.5f        * xi  * xp1 * xm2;
  float w3 =  (1.0f/6.0f) * xi  * xp1 * xm1;
  return ((w0*y0 + w1*y1) + w2*y2) + w3*y3;
}
__global__ void k_tabFine(const float* __restrict__ Gtab, float* __restrict__ TabF){
  int m = blockIdx.x*blockDim.x + threadIdx.x;
  if (m >= T_STEPS*FKN) return;
  int t = m / FKN;
  int c = m - t*FKN;
  TabF[m] = cubicEval(Gtab + t*UKNOTS, c);
}

// linear interp on scalar fine table (LDS)
__device__ __forceinline__ float interpS(const float* __restrict__ tab, float s){
  float x = sqrtf(s) * 2048.0f;
  float cf = floorf(x);
  cf = fminf(cf, 2047.0f);
  int c = (int)cf;
  float xi = x - cf;
  float y0 = tab[c], y1 = tab[c+1];
  return fmaf(xi, y1 - y0, y0);
}

// ---------------- kernel 5: sequential particle filter (single block, 1024 thr) ----------------
// R9 structure exactly (vHist in phase 1, plain float4 stores), with the single isolated
// change: B1/B3 are lgkm-only barriers (no global-memory dependence crosses them).
// B2 stays __syncthreads (full drain) — it orders idxG atomics + socP before the gather.
__global__ __launch_bounds__(1024) void k_filter(
    const float* __restrict__ soc_init, const float* __restrict__ current,
    const float* __restrict__ vmeas,   const float* __restrict__ Ecrit,
    const float* __restrict__ TabF,    const float* __restrict__ noiseTab,
    const float* __restrict__ u0Tab,   int* __restrict__ idxG,
    float* __restrict__ vHist, float* __restrict__ sHist,
    long strideT, long strideP, float* __restrict__ lossOut)
{
  __shared__ __align__(16) float socP[N_PART];     // 32 KiB (exact f32 propagated state)
  __shared__ __align__(16) float tabF[2][2052];    // 16.4 KiB dbuf
  __shared__ float ddW[16];
  __shared__ float sWv[16];

  const int tid = threadIdx.x;
  const int lane = tid & 63;
  const int wv = tid >> 6;
  const float ec = Ecrit[0];

  // prologue
  tabF[0][tid]      = TabF[tid];
  tabF[0][1024+tid] = TabF[1024+tid];
  if (tid == 0) tabF[0][2048] = TabF[2048];
  const float4* nzp = (const float4*)noiseTab + tid*2;
  float4 nzA = nzp[0], nzB = nzp[1];
  float soc[8], V[8];
  __syncthreads();
  #pragma unroll
  for (int k=0;k<8;k++){
    float s = soc_init[tid*8+k];
    soc[k] = s;
    V[k] = interpS(tabF[0], s);
  }
  float loss = 0.0f;
  float Iprev = current[0];

  for (int t=0; t<T_STEPS; t++){
    const int cur = t & 1, nxt = cur ^ 1;
    const int tagBase = t << 13;

    // prefetch next-step table + noise into registers
    int tn = (t+1 < T_STEPS) ? t+1 : t;
    const float* tRow = TabF + (size_t)tn * FKN;
    float pf0 = tRow[tid];
    float pf1 = tRow[1024+tid];
    float pf2 = 0.0f;
    if (tid == 0) pf2 = tRow[2048];
    const float4* nzn = (const float4*)(noiseTab + (size_t)tn*N_PART) + tid*2;
    float4 nzA2 = nzn[0], nzB2 = nzn[1];

    float It = current[t];
    float vm = vmeas[t];
    float u0 = u0Tab[t];
    float coef = -(Iprev / 26267.160775850585f) * ec;
    float nz[8] = {nzA.x,nzA.y,nzA.z,nzA.w,nzB.x,nzB.y,nzB.z,nzB.w};
    const float* tf = tabF[cur];

    // ---- phase 1: propagate + measure (socP write in LDS, exact f32) ----
    float dd[8];
    float dmin = INFINITY;
    #pragma unroll
    for (int k=0;k<8;k++){
      float s = fmaf(V[k], coef, soc[k]);
      s = s + nz[k];
      s = fminf(1.0f, fmaxf(s, 1e-10f));
      socP[tid*8+k] = s;
      float Vn = interpS(tf, s);
      V[k] = Vn;
      float d = Vn - vm;
      float q = d*d;
      dd[k] = q;
      dmin = fminf(dmin, q);
    }
    if (strideP == 1){
      float4 a = {V[0],V[1],V[2],V[3]}, b = {V[4],V[5],V[6],V[7]};
      float4* dst = (float4*)(vHist + (size_t)t*strideT + tid*8);
      dst[0] = a; dst[1] = b;
    } else {
      #pragma unroll
      for (int k=0;k<8;k++) vHist[(size_t)t*strideT + (size_t)(tid*8+k)*strideP] = V[k];
    }

    // wave min + exp prefix (wave frame)
    #pragma unroll
    for (int off=1; off<64; off<<=1) dmin = fminf(dmin, __shfl_xor(dmin, off));
    float ebase = DD2E * dmin;
    float run = 0.0f, cp[8];
    #pragma unroll
    for (int k=0;k<8;k++){
      float e = exp2f(fmaf(dd[k], -DD2E, ebase));
      run += e;
      cp[k] = run;
    }
    float sc = run;
    #pragma unroll
    for (int off=1; off<64; off<<=1){
      float o = __shfl_up(sc, (unsigned)off);
      if (lane >= off) sc += o;
    }
    float excl = __shfl_up(sc, 1);       // bitwise == prev lane's inclusive sc
    if (lane == 0) excl = 0.0f;
    if (lane == 63){ ddW[wv] = dmin; sWv[wv] = sc; }
    // commit prefetched table into the other buffer
    tabF[nxt][tid]      = pf0;
    tabF[nxt][1024+tid] = pf1;
    if (tid == 0) tabF[nxt][2048] = pf2;
    BAR_LGKM();                          // B1 (LDS-only ordering; vHist store overlaps)

    // ---- combine wave stats (lanes 0..15 of every wave, redundant; normalized frames) ----
    float baseN = 0.0f, inclN = 0.0f, scaleN = 0.0f;
    if (lane < 16){
      float dv = ddW[lane];
      float dG = dv;
      #pragma unroll
      for (int off=1; off<16; off<<=1) dG = fminf(dG, __shfl_xor(dG, off));
      float ew = exp2f(-DD2E * (dv - dG));
      float pf = sWv[lane] * ew;
      #pragma unroll
      for (int off=1; off<16; off<<=1){
        float o = __shfl_up(pf, (unsigned)off);
        if (lane >= off) pf += o;
      }
      float Sv = __shfl(pf, 15);
      float invS = 1.0f / Sv;
      float pfEx = __shfl_up(pf, 1);
      if (lane == 0) pfEx = 0.0f;
      baseN  = pfEx * invS;              // exclusive block prefix, normalized
      inclN  = pf * invS;                // inclusive; bitwise == next wave's baseN
      scaleN = ew * invS;
      if (tid == 0)
        loss = ((loss + (LOGNU - DD2LW*dG)) + logf(Sv)) - LOG8192;
    }
    float b0  = __shfl(baseN, wv);
    float bI  = __shfl(inclN, wv);
    float scl = __shfl(scaleN, wv);

    // ---- slot inversion + tagged GLOBAL scatter (bitwise-exact seams, owners only) ----
    float scl8 = scl * 8192.0f;
    float b8   = fmaf(b0, 8192.0f, -u0);       // wave base in slot units
    float bth  = fmaf(excl, scl8, b8);
    int aPrev = __float2int_rd(bth);
    if (aPrev < -1) aPrev = -1;
    #pragma unroll
    for (int k=0;k<8;k++){
      int i = tid*8 + k;
      int a;
      if (i == N_PART-1){
        a = N_PART-1;
      } else if (k == 7){
        if (lane == 63) a = __float2int_rd(fmaf(bI, 8192.0f, -u0));  // == next wave's aPrev
        else            a = __float2int_rd(fmaf(sc, scl8, b8));      // == next thread's aPrev
        if (a > N_PART-1) a = N_PART-1;
      } else {
        a = __float2int_rd(fmaf(cp[k], scl8, bth));
        if (a > N_PART-1) a = N_PART-1;
      }
      if (a < aPrev) a = aPrev;
      int st = aPrev + 1;
      if (a >= st){                              // owners only
        int tag = tagBase + i;
        atomicMax(&idxG[st], tag);
        for (int r = (st>>9)+1; (r<<9) <= a; ++r)
          atomicMax(&idxG[r<<9], tag);           // 512-region anchors
      }
      aPrev = a;
    }
    __syncthreads();                     // B2 (full drain: idxG atomics + socP ordering)

    // ---- slot phase: agent-scope idxG reads (L1-bypass), wave max-scan, LDS gather ----
    unsigned long long q01 = __hip_atomic_load((unsigned long long*)&idxG[tid*8+0], __ATOMIC_RELAXED, __HIP_MEMORY_SCOPE_AGENT);
    unsigned long long q23 = __hip_atomic_load((unsigned long long*)&idxG[tid*8+2], __ATOMIC_RELAXED, __HIP_MEMORY_SCOPE_AGENT);
    unsigned long long q45 = __hip_atomic_load((unsigned long long*)&idxG[tid*8+4], __ATOMIC_RELAXED, __HIP_MEMORY_SCOPE_AGENT);
    unsigned long long q67 = __hip_atomic_load((unsigned long long*)&idxG[tid*8+6], __ATOMIC_RELAXED, __HIP_MEMORY_SCOPE_AGENT);
    int sl[8] = { (int)(uint32_t)q01, (int)(uint32_t)(q01>>32),
                  (int)(uint32_t)q23, (int)(uint32_t)(q23>>32),
                  (int)(uint32_t)q45, (int)(uint32_t)(q45>>32),
                  (int)(uint32_t)q67, (int)(uint32_t)(q67>>32) };
    int pm = sl[0];
    #pragma unroll
    for (int k=1;k<8;k++) pm = max(pm, sl[k]);
    int scn = pm;
    #pragma unroll
    for (int off=1; off<64; off<<=1){
      int o = __shfl_up(scn, (unsigned)off);
      if (lane >= off) scn = max(scn, o);
    }
    int ex = __shfl_up(scn, 1);
    if (lane == 0) ex = -1;              // wave-chunk start covered by 512-anchor
    float sn[8];
    int run2 = ex;
    #pragma unroll
    for (int k=0;k<8;k++){
      run2 = max(run2, sl[k]);
      int idx = run2 - tagBase;
      if (idx < 0 || idx > N_PART-1) idx = tid*8+k;   // safety net (should not trigger)
      sn[k] = socP[idx];
    }
    if (strideP == 1){
      float4 a = {sn[0],sn[1],sn[2],sn[3]}, b = {sn[4],sn[5],sn[6],sn[7]};
      float4* dst = (float4*)(sHist + (size_t)t*strideT + tid*8);
      dst[0] = a; dst[1] = b;
    } else {
      #pragma unroll
      for (int k=0;k<8;k++) sHist[(size_t)t*strideT + (size_t)(tid*8+k)*strideP] = sn[k];
    }
    #pragma unroll
    for (int k=0;k<8;k++) soc[k] = sn[k];
    Iprev = It;
    nzA = nzA2; nzB = nzB2;
    BAR_LGKM();                          // B3 (WAR on socP; LDS-only ordering)
  }
  if (tid == 0) lossOut[0] = loss;
}

// ---------------- kernel 6: (T,N) -> (N,T) transpose ----------------
__global__ void k_transpose(const float* __restrict__ vS, const float* __restrict__ sS,
                            float* __restrict__ outV, float* __restrict__ outS){
  __shared__ float tile[32][33];
  const float* src = blockIdx.z ? sS : vS;
  float* dst = blockIdx.z ? outS : outV;
  int t0 = blockIdx.x*32, n0 = blockIdx.y*32;
  int tx = threadIdx.x, ty = threadIdx.y;
  #pragma unroll
  for (int r=0;r<4;r++)
    tile[ty+8*r][tx] = src[(size_t)(t0+ty+8*r)*N_PART + n0 + tx];
  __syncthreads();
  #pragma unroll
  for (int r=0;r<4;r++)
    dst[(size_t)(n0+ty+8*r)*T_STEPS + t0 + tx] = tile[tx][ty+8*r];
}

extern "C" void kernel_launch(void* const* d_in, const int* in_sizes, int n_in,
                              void* d_out, int out_size, void* d_ws, size_t ws_size,
                              hipStream_t stream){
  const float* soc_init = (const float*)d_in[0];
  const float* current  = (const float*)d_in[1];
  const float* vmeas    = (const float*)d_in[2];
  const float* W1 = (const float*)d_in[3];
  const float* b1 = (const float*)d_in[4];
  const float* W2 = (const float*)d_in[5];
  const float* b2 = (const float*)d_in[6];
  const float* W3 = (const float*)d_in[7];
  const float* b3 = (const float*)d_in[8];
  const float* Ec = (const float*)d_in[9];

  float* outLoss = (float*)d_out;
  float* outV = outLoss + 1;
  float* outS = outV + (size_t)N_PART*T_STEPS;

  char* p = (char*)d_ws;
  auto carve = [&](size_t bytes)->char*{ char* r = p; p += (bytes + 255) & ~(size_t)255; return r; };
  uint32_t* knKeys  = (uint32_t*)carve((size_t)2*T_STEPS*4);
  float* u0Tab      = (float*)carve((size_t)T_STEPS*4);
  int*   idxG       = (int*)carve((size_t)N_PART*4);     // 0xAA poison < 0 == stale, no init
  float* Zpart      = (float*)carve((size_t)4*M2TOT*4);
  float* Z2D        = (float*)carve((size_t)M2TOT*4);
  float* Gtab       = (float*)carve((size_t)T_STEPS*UKNOTS*4);
  float* TabF       = (float*)carve((size_t)T_STEPS*FKN*4);
  float* noiseTab   = (float*)carve((size_t)N_PART*T_STEPS*4);
  float* vS         = (float*)carve((size_t)N_PART*T_STEPS*4);
  float* sS         = (float*)carve((size_t)N_PART*T_STEPS*4);
  bool useScratch   = ((size_t)(p - (char*)d_ws) <= ws_size);

  k_keys<<<dim3((T_STEPS+255)/256), dim3(256), 0, stream>>>(knKeys, u0Tab);
  k_noise<<<dim3(T_STEPS), dim3(256), 0, stream>>>(knKeys, noiseTab);
  k_gemm<<<dim3((M2TOT+63)/64, 4), dim3(256), 0, stream>>>(W1, b1, W2, b2, W3, Zpart);
  k_tabZ<<<dim3((M2TOT+255)/256), dim3(256), 0, stream>>>(Zpart, b3, Z2D);
  k_tabG<<<dim3((T_STEPS*UKNOTS+255)/256), dim3(256), 0, stream>>>(Z2D, current, Gtab);
  k_tabFine<<<dim3((T_STEPS*FKN+255)/256), dim3(256), 0, stream>>>(Gtab, TabF);

  if (useScratch){
    k_filter<<<dim3(1), dim3(1024), 0, stream>>>(soc_init, current, vmeas, Ec, TabF, noiseTab,
                                                 u0Tab, idxG, vS, sS, (long)N_PART, 1L, outLoss);
    k_transpose<<<dim3(T_STEPS/32, N_PART/32, 2), dim3(32,8), 0, stream>>>(vS, sS, outV, outS);
  } else {
    k_filter<<<dim3(1), dim3(1024), 0, stream>>>(soc_init, current, vmeas, Ec, TabF, noiseTab,
                                                 u0Tab, idxG, outV, outS, 1L, (long)T_STEPS, outLoss);
  }
}